// Round 1
// baseline (33896.094 us; speedup 1.0000x reference)
//
#include <hip/hip_runtime.h>
#include <math.h>

#define BB 32
#define SSS 1024
#define EE 256
#define HHH 256
#define TEAM 8
#define CHUNK 128   // SSS / TEAM
#define NTHR 512
#define CPAD 129    // padded slot stride for transposed ctx_proj tile
#define THETA 3e-5f // refinement margin: >>10x the fp32 score-noise bound (~1e-6)
#define MAXCAND 8

#define NEG_INF (-__builtin_huge_valf())

__device__ __forceinline__ double sigd(double x) {
  return 1.0 / (1.0 + exp(-x));
}

// Fast fp32 tanh: 1 - 2/(1+e^{2x}) via v_exp_f32 + v_rcp_f32.
// abs error ~5e-7; safe at +-inf (e=inf -> 1, e=0 -> -1), no NaN path.
__device__ __forceinline__ float fast_tanhf(float x) {
  float e = __expf(2.0f * x);
  return 1.0f - 2.0f * __builtin_amdgcn_rcpf(1.0f + e);
}

// Cross-block data exchange: relaxed agent-scope atomics. These read/write the
// device coherence point directly, so barriers need no L2 inv/writeback for
// data correctness.
__device__ __forceinline__ void gstore(float* p, float v) {
  __hip_atomic_store(p, v, __ATOMIC_RELAXED, __HIP_MEMORY_SCOPE_AGENT);
}
__device__ __forceinline__ float gload(const float* p) {
  return __hip_atomic_load(p, __ATOMIC_RELAXED, __HIP_MEMORY_SCOPE_AGENT);
}
__device__ __forceinline__ void gstored(double* p, double v) {
  __hip_atomic_store(p, v, __ATOMIC_RELAXED, __HIP_MEMORY_SCOPE_AGENT);
}
__device__ __forceinline__ double gloadd(const double* p) {
  return __hip_atomic_load(p, __ATOMIC_RELAXED, __HIP_MEMORY_SCOPE_AGENT);
}

// Monotonic-counter team barrier (8 blocks). Release on arrival orders the
// arriving block's prior (atomic) stores; spin is RELAXED — no per-poll cache
// maintenance. Data freshness comes from agent-scope atomic data ops.
__device__ __forceinline__ void team_bar(int* cnt, int target) {
  __syncthreads();
  if (threadIdx.x == 0) {
    __hip_atomic_fetch_add(cnt, 1, __ATOMIC_RELEASE, __HIP_MEMORY_SCOPE_AGENT);
    while (__hip_atomic_load(cnt, __ATOMIC_RELAXED, __HIP_MEMORY_SCOPE_AGENT) < target) {}
  }
  __syncthreads();
}

__global__ __launch_bounds__(NTHR, 2) void ptrnet(
    const float* __restrict__ enc, const float* __restrict__ dec0,
    const float* __restrict__ h0, const float* __restrict__ c0,
    const float* __restrict__ context,
    const float* __restrict__ W_ih, const float* __restrict__ b_ih,
    const float* __restrict__ W_hh, const float* __restrict__ b_hh,
    const float* __restrict__ W_out, const float* __restrict__ b_out,
    const float* __restrict__ Wa_in, const float* __restrict__ ba_in,
    const float* __restrict__ Wa_ctx, const float* __restrict__ ba_ctx,
    const float* __restrict__ v,
    float* __restrict__ out,
    int* __restrict__ barp,
    float* __restrict__ hbuf, float* __restrict__ htbuf,
    float* __restrict__ pinp, float* __restrict__ stats,
    float* __restrict__ accb, double* __restrict__ refws)
{
  // ---- LDS (~149 KB) ----
  __shared__ __align__(16) float cpT[HHH * CPAD];   // ctx_proj chunk, [h][slot], padded
  __shared__ double dsc[256];                        // fp64 refine scratch
  __shared__ __align__(8) float ivp[HHH * 2];       // interleaved (inp, v) fp32
  __shared__ double inp_d[HHH];                      // fp64 inp for refinement
  __shared__ double gact[128];                       // fp64 gate activations
  __shared__ float attn_s[HHH];
  __shared__ float ht_s[HHH];
  __shared__ __align__(16) float hx_s[HHH];
  __shared__ float scratch[NTHR];
  __shared__ float bg_s[128];
  __shared__ float bain_s[HHH];
  __shared__ float v_s[HHH];
  __shared__ float score_s[CHUNK];
  __shared__ float w_s[CHUNK];
  __shared__ float alive_s[CHUNK];
  __shared__ float bo_s[32];
  __shared__ float htl_s[32];
  __shared__ double c_d[32];                         // fp64 cell-state slice
  __shared__ float scale8_s[TEAM];
  __shared__ float mg_sh, lg_sh, mc_sh, m2_sh, cutoff_sh;
  __shared__ int idx_sh, bi_sh, rf_sh, ncand_sh;
  __shared__ int cand_s[MAXCAND];

  const int tid = threadIdx.x;
  const int b = blockIdx.x & 31;   // batch
  const int m = blockIdx.x >> 5;   // team member 0..7
  int* cnt = barp + b * 32;                 // 128B-strided barrier counters
  int* hcnt = barp + 1024 + b * 32;         // 128B-strided h-handoff counters

  // ============ one-time: ctx_proj chunk -> cpT (transposed, fp64 acc) ============
  {
    float* raw = cpT;
    const float* ctxp = context + ((size_t)b * SSS + (size_t)m * CHUNK) * HHH;
    for (int i = tid; i < CHUNK * HHH; i += NTHR) raw[i] = ctxp[i];
    __syncthreads();
    const int cc = tid & 255;
    const int rgc = tid >> 8;  // row-group: rows rgc*64 ..
    double acc[2][32];
    double bc = (double)ba_ctx[cc];
    for (int half = 0; half < 2; ++half) {
#pragma unroll
      for (int k = 0; k < 32; ++k) acc[half][k] = 0.0;
      for (int h = 0; h < HHH; ++h) {
        double w = (double)Wa_ctx[h * HHH + cc];
        const float* base = &raw[(rgc * 64 + half * 32) * HHH + h];
#pragma unroll
        for (int k = 0; k < 32; ++k) acc[half][k] = fma((double)base[k * HHH], w, acc[half][k]);
      }
    }
    __syncthreads();  // all raw reads complete before transposed overwrite
#pragma unroll
    for (int half = 0; half < 2; ++half)
#pragma unroll
      for (int k = 0; k < 32; ++k) {
        int row = rgc * 64 + half * 32 + k;
        cpT[cc * CPAD + row] = (float)(acc[half][k] + bc);
      }
  }

  // ============ persistent weight registers ============
  const int q = tid & 127, rg = tid >> 7;                 // gates
  const int gcol = ((q >> 5) * 256) + m * 32 + (q & 31);
  float w_ih_r[64], w_hh_r[64];
#pragma unroll
  for (int k = 0; k < 64; ++k) {
    w_ih_r[k] = W_ih[(size_t)(rg * 64 + k) * 1024 + gcol];
    w_hh_r[k] = W_hh[(size_t)(rg * 64 + k) * 1024 + gcol];
  }
  const int hp = tid & 255, rh = tid >> 8;                // inp partial
  float w_ain_r[16];
#pragma unroll
  for (int k = 0; k < 16; ++k)
    w_ain_r[k] = Wa_in[(size_t)(m * 32 + rh * 16 + k) * HHH + hp];
  const int c2 = tid & 31, rgo = tid >> 5;                // h_out slice
  float w_out_r[32];
#pragma unroll
  for (int k = 0; k < 32; ++k)
    w_out_r[k] = W_out[(size_t)(rgo * 32 + k) * HHH + m * 32 + c2];

  // ============ LDS init ============
  if (tid < 128) {
    int j = ((tid >> 5) * 256) + m * 32 + (tid & 31);
    bg_s[tid] = b_ih[j] + b_hh[j];
    alive_s[tid] = 1.0f;
  }
  if (tid < 256) { bain_s[tid] = ba_in[tid]; v_s[tid] = v[tid]; }
  if (tid < 32)  { bo_s[tid] = b_out[m * 32 + tid]; c_d[tid] = (double)c0[b * HHH + m * 32 + tid]; }
  __syncthreads();

  int bart = 0;

  for (int t = 0; t < SSS; ++t) {
    // ------- A: x-gates (overlap h handoff) -> LSTM(fp64 state) -> pinp partial -------
    // x row read directly through caches (read-only, L2/MALL-resident).
    const float* xrow = (t == 0) ? (dec0 + (size_t)b * EE)
                                 : (enc + ((size_t)b * SSS + (size_t)idx_sh) * EE);
    float g = 0.0f;
    {
      const float4* x4 = reinterpret_cast<const float4*>(xrow + rg * 64);
#pragma unroll
      for (int k = 0; k < 16; ++k) {
        float4 xv = x4[k];
        g = fmaf(w_ih_r[4 * k + 0], xv.x, g);
        g = fmaf(w_ih_r[4 * k + 1], xv.y, g);
        g = fmaf(w_ih_r[4 * k + 2], xv.z, g);
        g = fmaf(w_ih_r[4 * k + 3], xv.w, g);
      }
    }
    // h handoff: producers released hcnt right after hbuf stores in C(t-1);
    // only consumers wait, and the x-part work above hides most of the latency.
    if (t == 0) {
      if (tid < 256) hx_s[tid] = h0[b * HHH + tid];
    } else if (tid == 0) {
      while (__hip_atomic_load(hcnt, __ATOMIC_RELAXED, __HIP_MEMORY_SCOPE_AGENT) < TEAM * t) {}
    }
    __syncthreads();
    if (t != 0 && tid < 256) hx_s[tid] = gload(&hbuf[b * HHH + tid]);
    __syncthreads();
    {
      const float4* h4 = reinterpret_cast<const float4*>(&hx_s[rg * 64]);
#pragma unroll
      for (int k = 0; k < 16; ++k) {
        float4 hv = h4[k];
        g = fmaf(w_hh_r[4 * k + 0], hv.x, g);
        g = fmaf(w_hh_r[4 * k + 1], hv.y, g);
        g = fmaf(w_hh_r[4 * k + 2], hv.z, g);
        g = fmaf(w_hh_r[4 * k + 3], hv.w, g);
      }
      scratch[tid] = g;  // rg*128+q == tid
    }
    __syncthreads();
    // parallel fp64 gate activations: each of 128 threads activates its own gate
    if (tid < 128) {
      float gsv = scratch[tid] + scratch[128 + tid] + scratch[256 + tid] + scratch[384 + tid] + bg_s[tid];
      double gd = (double)gsv;
      gact[tid] = (tid >= 64 && tid < 96) ? tanh(gd) : sigd(gd);  // [64,96) = g-gate
    }
    __syncthreads();
    if (tid < 32) {
      double cn = gact[32 + tid] * c_d[tid] + gact[tid] * gact[64 + tid];
      double ht = gact[96 + tid] * tanh(cn);
      c_d[tid] = cn;
      float htf = (float)ht;
      htl_s[tid] = htf;
      gstore(&htbuf[b * HHH + m * 32 + tid], htf);
    }
    __syncthreads();
    {
      float p = 0.0f;
#pragma unroll
      for (int k = 0; k < 16; ++k) p = fmaf(w_ain_r[k], htl_s[rh * 16 + k], p);
      scratch[rh * 256 + hp] = p;
    }
    __syncthreads();
    if (tid < 256) gstore(&pinp[((b * TEAM) + m) * HHH + tid], scratch[tid] + scratch[256 + tid]);
    bart += TEAM; team_bar(cnt, bart);

    // ------- B: thread-per-slot scores + chunk top-2 softmax stats + acc -------
    if (tid < 256) {
      double sd = (double)bain_s[tid];
#pragma unroll
      for (int w = 0; w < TEAM; ++w) sd += (double)gload(&pinp[((b * TEAM) + w) * HHH + tid]);
      inp_d[tid] = sd;
      ivp[2 * tid] = (float)sd; ivp[2 * tid + 1] = v_s[tid];
    }
    __syncthreads();
    {
      const int s = tid & 127, qq = tid >> 7;
      const float* cpc = &cpT[(qq * 64) * CPAD + s];
      const float2* iv = reinterpret_cast<const float2*>(&ivp[2 * qq * 64]);
      float acc0 = 0.0f, acc1 = 0.0f;
#pragma unroll 4
      for (int j = 0; j < 64; j += 2) {
        float2 iv0 = iv[j], iv1 = iv[j + 1];
        float t0 = fast_tanhf(iv0.x + cpc[j * CPAD]);
        float t1 = fast_tanhf(iv1.x + cpc[(j + 1) * CPAD]);
        acc0 = fmaf(iv0.y, t0, acc0);
        acc1 = fmaf(iv1.y, t1, acc1);
      }
      scratch[tid] = acc0 + acc1;  // qq*128+s == tid
    }
    __syncthreads();
    if (tid < 128)
      score_s[tid] = scratch[tid] + scratch[128 + tid] + scratch[256 + tid] + scratch[384 + tid];
    __syncthreads();
    if (tid < 64) {   // chunk top-2 (alive): v1 w/ first-occurrence idx, v2 value only
      float sa = (alive_s[tid] > 0.0f) ? score_s[tid] : NEG_INF;
      float sb = (alive_s[tid + 64] > 0.0f) ? score_s[tid + 64] : NEG_INF;
      float v1, v2; int i1;
      if (sb > sa) { v1 = sb; i1 = tid + 64; v2 = sa; }
      else         { v1 = sa; i1 = tid;      v2 = sb; }
#pragma unroll
      for (int d = 1; d < 64; d <<= 1) {
        float ov1 = __shfl_xor(v1, d); int oi1 = __shfl_xor(i1, d);
        float ov2 = __shfl_xor(v2, d);
        if (ov1 > v1 || (ov1 == v1 && oi1 < i1)) {
          v2 = fmaxf(v1, ov2); v1 = ov1; i1 = oi1;
        } else {
          v2 = fmaxf(v2, ov1);
        }
      }
      if (tid == 0) { mc_sh = v1; bi_sh = i1; m2_sh = v2; }
    }
    __syncthreads();
    if (tid < 128)
      w_s[tid] = (alive_s[tid] > 0.0f) ? __expf(score_s[tid] - mc_sh) : 0.0f;
    __syncthreads();
    if (tid < 64) {   // chunk l + stats write
      float l = w_s[tid] + w_s[tid + 64];
#pragma unroll
      for (int d = 1; d < 64; d <<= 1) l += __shfl_xor(l, d);
      if (tid == 0) {
        float* st = &stats[((b * TEAM) + m) * 4];
        gstore(&st[0], mc_sh);
        gstore(&st[1], l);
        gstore(&st[2], __int_as_float((mc_sh == NEG_INF) ? 0x7fffffff : (m * CHUNK + bi_sh)));
        gstore(&st[3], m2_sh);
      }
    }
    {
      const int h = tid & 255, sh = tid >> 8;
      const float* cpr = &cpT[h * CPAD + sh * 64];
      const float* wr = &w_s[sh * 64];
      float a = 0.0f;
#pragma unroll 8
      for (int j = 0; j < 64; ++j) a = fmaf(wr[j], cpr[j], a);
      scratch[sh * 256 + h] = a;
    }
    __syncthreads();
    if (tid < 256) gstore(&accb[((b * TEAM) + m) * HHH + tid], scratch[tid] + scratch[256 + tid]);
    bart += TEAM; team_bar(cnt, bart);

    // ------- C: combine (top-2 + margin) -> [refine] -> attn -> h_out -> outputs -------
    if (tid < 32)  // parallel stats gather: scratch[w*4+j]
      scratch[tid] = gload(&stats[((b * TEAM) + (tid >> 2)) * 4 + (tid & 3)]);
    __syncthreads();
    if (tid == 0) {
      float g1 = NEG_INF, g2 = NEG_INF; int gi = 0x7fffffff;
      float lg = 0.0f;
      float mcv[TEAM], lcv[TEAM];
#pragma unroll
      for (int w = 0; w < TEAM; ++w) {
        mcv[w] = scratch[w * 4 + 0]; lcv[w] = scratch[w * 4 + 1];
        int biv = __float_as_int(scratch[w * 4 + 2]); float v2v = scratch[w * 4 + 3];
        if (lcv[w] > 0.0f) {
          if (mcv[w] > g1 || (mcv[w] == g1 && biv < gi)) {
            g2 = fmaxf(g1, v2v); g1 = mcv[w]; gi = biv;
          } else {
            g2 = fmaxf(g2, mcv[w]);
          }
        }
      }
#pragma unroll
      for (int w = 0; w < TEAM; ++w) {
        float sw = (lcv[w] > 0.0f) ? __expf(mcv[w] - g1) : 0.0f;
        scale8_s[w] = sw; lg += lcv[w] * sw;
      }
      mg_sh = g1; lg_sh = lg; idx_sh = gi;
      rf_sh = (g2 > g1 - THETA) ? 1 : 0;   // margin < THETA -> exact refinement
      cutoff_sh = g1 - THETA;
    }
    __syncthreads();

    if (rf_sh) {
      // -- exact fp64 re-scoring of all near-top alive slots (deterministic team-wide) --
      if (tid == 0) {
        int nc = 0;
        for (int s2 = 0; s2 < CHUNK; ++s2)
          if (alive_s[s2] > 0.0f && score_s[s2] > cutoff_sh && nc < MAXCAND)
            cand_s[nc++] = s2;
        ncand_sh = nc;
      }
      __syncthreads();
      const int nc = ncand_sh;
      for (int ci = 0; ci < nc; ++ci) {
        const int slot = cand_s[ci];
        if (tid < 256) {
          const float* crow = context + ((size_t)b * SSS + (size_t)(m * CHUNK + slot)) * HHH;
          double acc = (double)ba_ctx[tid];
          for (int h2 = 0; h2 < HHH; ++h2)
            acc = fma((double)crow[h2], (double)Wa_ctx[h2 * HHH + tid], acc);
          double arg = inp_d[tid] + acc;
          dsc[tid] = (double)v_s[tid] * tanh(arg);
        }
        __syncthreads();
        if (tid < 64) {  // parallel fp64 reduce of 256 partials
          double se = dsc[tid] + dsc[tid + 64] + dsc[tid + 128] + dsc[tid + 192];
#pragma unroll
          for (int d = 1; d < 64; d <<= 1) se += __shfl_xor(se, d);
          if (tid == 0) {
            double* rw = &refws[(((size_t)b * TEAM) + m) * (1 + 2 * MAXCAND)];
            gstored(&rw[1 + 2 * ci], (double)(m * CHUNK + slot));
            gstored(&rw[2 + 2 * ci], se);
          }
        }
        __syncthreads();
      }
      if (tid == 0)
        gstored(&refws[(((size_t)b * TEAM) + m) * (1 + 2 * MAXCAND)], (double)nc);
      bart += TEAM; team_bar(cnt, bart);
      if (tid == 0) {
        double bs = -1.0e300; int bi2 = 0x7fffffff;
#pragma unroll
        for (int w = 0; w < TEAM; ++w) {
          const double* rw = &refws[(((size_t)b * TEAM) + w) * (1 + 2 * MAXCAND)];
          int wn = (int)gloadd(&rw[0]);
          for (int j2 = 0; j2 < wn; ++j2) {
            int ii = (int)gloadd(&rw[1 + 2 * j2]); double sv = gloadd(&rw[2 + 2 * j2]);
            if (sv > bs || (sv == bs && ii < bi2)) { bs = sv; bi2 = ii; }
          }
        }
        idx_sh = bi2;
      }
      __syncthreads();
    }

    if (tid < 256) {
      float a = 0.0f;
#pragma unroll
      for (int w = 0; w < TEAM; ++w) a += gload(&accb[((b * TEAM) + w) * HHH + tid]) * scale8_s[w];
      attn_s[tid] = a / lg_sh;
      ht_s[tid] = gload(&htbuf[b * HHH + tid]);
    }
    __syncthreads();
    {
      float hpart = 0.0f;
#pragma unroll
      for (int k = 0; k < 32; ++k) {
        int r = rgo * 32 + k;
        float vr = (r < 256) ? attn_s[r] : ht_s[r - 256];
        hpart = fmaf(w_out_r[k], vr, hpart);
      }
      scratch[rgo * 32 + c2] = hpart;
    }
    __syncthreads();
    if (tid < 32) {
      float s = bo_s[tid];
#pragma unroll
      for (int j = 0; j < 16; ++j) s += scratch[j * 32 + tid];
      gstore(&hbuf[b * HHH + m * 32 + tid], tanhf(s));
    }
    __syncthreads();   // hbuf stores drained (vmcnt 0 at barrier) before release
    if (tid == 0)      // release h to next step's consumers — nobody waits here
      __hip_atomic_fetch_add(hcnt, 1, __ATOMIC_RELEASE, __HIP_MEMORY_SCOPE_AGENT);
    if (tid < 128) {
      float sc_ = score_s[tid];
      float al = (alive_s[tid] > 0.0f) ? __expf(sc_ - mg_sh) / lg_sh : 0.0f;
      __builtin_nontemporal_store(al,
          &out[(size_t)b * (SSS * SSS) + (size_t)t * SSS + m * CHUNK + tid]);
    }
    if (m == 0 && tid == 0)
      __builtin_nontemporal_store((float)idx_sh,
          &out[(size_t)BB * SSS * SSS + (size_t)b * SSS + t]);
    __syncthreads();   // alpha writes read alive_s before the clear below
    if (tid == 0 && (idx_sh >> 7) == m) alive_s[idx_sh & 127] = 0.0f;
    // no team barrier here: stats/accb/pinp WAR is covered by barriers 1/2 of
    // step t+1; the hbuf RAW is covered by the hcnt handoff at the top of A.
  }
}

extern "C" void kernel_launch(void* const* d_in, const int* in_sizes, int n_in,
                              void* d_out, int out_size, void* d_ws, size_t ws_size,
                              hipStream_t stream) {
  (void)in_sizes; (void)n_in; (void)out_size; (void)ws_size;
  const float* enc     = (const float*)d_in[0];
  const float* dec0    = (const float*)d_in[1];
  const float* h0      = (const float*)d_in[2];
  const float* c0      = (const float*)d_in[3];
  const float* context = (const float*)d_in[4];
  const float* W_ih    = (const float*)d_in[5];
  const float* b_ih    = (const float*)d_in[6];
  const float* W_hh    = (const float*)d_in[7];
  const float* b_hh    = (const float*)d_in[8];
  const float* W_out   = (const float*)d_in[9];
  const float* b_out   = (const float*)d_in[10];
  const float* Wa_in   = (const float*)d_in[11];
  const float* ba_in   = (const float*)d_in[12];
  const float* Wa_ctx  = (const float*)d_in[13];
  const float* ba_ctx  = (const float*)d_in[14];
  const float* v       = (const float*)d_in[15];

  char* wsb   = (char*)d_ws;
  int*   barp  = (int*)wsb;                         // 8192 B: bart + hcnt lines
  float* hbuf  = (float*)(wsb + 8192);              // [32][256]           32768 B
  float* htbuf = hbuf + 32 * 256;                   // [32][256]           32768 B
  float* pinp  = htbuf + 32 * 256;                  // [32][8][256]       262144 B
  float* stats = pinp + 32 * 8 * 256;               // [32][8][4]           4096 B
  float* accb  = stats + 32 * 8 * 4;                // [32][8][256]       262144 B
  double* refws = (double*)(accb + 32 * 8 * 256);   // [32][8][17] dbl     34816 B  (tot ~637 KB)

  hipMemsetAsync(d_ws, 0, 8192, stream);            // reset barrier + handoff counters
  hipLaunchKernelGGL(ptrnet, dim3(256), dim3(NTHR), 0, stream,
                     enc, dec0, h0, c0, context,
                     W_ih, b_ih, W_hh, b_hh, W_out, b_out,
                     Wa_in, ba_in, Wa_ctx, ba_ctx, v,
                     (float*)d_out, barp, hbuf, htbuf, pinp, stats, accb, refws);
}

// Round 2
// 25147.290 us; speedup vs baseline: 1.3479x; 1.3479x over previous
//
#include <hip/hip_runtime.h>
#include <math.h>

#define BB 32
#define SSS 1024
#define EE 256
#define HHH 256
#define TEAM 8
#define CHUNK 128   // SSS / TEAM
#define NTHR 512
#define CPAD 129    // padded slot stride for transposed ctx_proj tile
#define THETA 3e-5f // refinement margin: >>10x the fp32 score-noise bound (~1e-6)
#define MAXCAND 8

#define NEG_INF (-__builtin_huge_valf())

__device__ __forceinline__ double sigd(double x) {
  return 1.0 / (1.0 + exp(-x));
}

// Fast fp32 tanh: 1 - 2/(1+e^{2x}) via v_exp_f32 + v_rcp_f32.
// abs error ~5e-7; safe at +-inf, no NaN path. Score noise stays ~1e-6 << THETA.
__device__ __forceinline__ float fast_tanhf(float x) {
  float e = __expf(2.0f * x);
  return 1.0f - 2.0f * __builtin_amdgcn_rcpf(1.0f + e);
}

// Cross-block data exchange: relaxed agent-scope atomics. These read/write the
// device coherence point directly, so barriers need no L2 inv/writeback for
// data correctness.
__device__ __forceinline__ void gstore(float* p, float v) {
  __hip_atomic_store(p, v, __ATOMIC_RELAXED, __HIP_MEMORY_SCOPE_AGENT);
}
__device__ __forceinline__ float gload(const float* p) {
  return __hip_atomic_load(p, __ATOMIC_RELAXED, __HIP_MEMORY_SCOPE_AGENT);
}
__device__ __forceinline__ void gstored(double* p, double v) {
  __hip_atomic_store(p, v, __ATOMIC_RELAXED, __HIP_MEMORY_SCOPE_AGENT);
}
__device__ __forceinline__ double gloadd(const double* p) {
  return __hip_atomic_load(p, __ATOMIC_RELAXED, __HIP_MEMORY_SCOPE_AGENT);
}

// Monotonic-counter team barrier (8 blocks). Release on arrival orders the
// arriving block's prior (atomic) stores; spin is RELAXED — no per-poll cache
// maintenance. Lockstep (3 barriers/step) keeps spin windows minimal: round-1
// showed that removing one barrier widens drift and costs MORE than it saves
// (FETCH 391->2269 MB of poll traffic, dur +1.5us/step).
__device__ __forceinline__ void team_bar(int* cnt, int target) {
  __syncthreads();
  if (threadIdx.x == 0) {
    __hip_atomic_fetch_add(cnt, 1, __ATOMIC_RELEASE, __HIP_MEMORY_SCOPE_AGENT);
    while (__hip_atomic_load(cnt, __ATOMIC_RELAXED, __HIP_MEMORY_SCOPE_AGENT) < target) {}
  }
  __syncthreads();
}

__global__ __launch_bounds__(NTHR, 2) void ptrnet(
    const float* __restrict__ enc, const float* __restrict__ dec0,
    const float* __restrict__ h0, const float* __restrict__ c0,
    const float* __restrict__ context,
    const float* __restrict__ W_ih, const float* __restrict__ b_ih,
    const float* __restrict__ W_hh, const float* __restrict__ b_hh,
    const float* __restrict__ W_out, const float* __restrict__ b_out,
    const float* __restrict__ Wa_in, const float* __restrict__ ba_in,
    const float* __restrict__ Wa_ctx, const float* __restrict__ ba_ctx,
    const float* __restrict__ v,
    float* __restrict__ out,
    int* __restrict__ barp,
    float* __restrict__ hbuf, float* __restrict__ htbuf,
    float* __restrict__ pinp, float* __restrict__ stats,
    float* __restrict__ accb, double* __restrict__ refws)
{
  // ---- LDS (~149 KB) ----
  __shared__ __align__(16) float cpT[HHH * CPAD];   // ctx_proj chunk, [h][slot], padded
  __shared__ double dsc[256];                        // fp64 refine scratch
  __shared__ __align__(8) float ivp[HHH * 2];       // interleaved (inp, v) fp32
  __shared__ double inp_d[HHH];                      // fp64 inp for refinement
  __shared__ double gact[128];                       // fp64 gate activations
  __shared__ float attn_s[HHH];
  __shared__ float ht_s[HHH];
  __shared__ __align__(16) float hx_s[HHH];
  __shared__ __align__(16) float x_s[EE];
  __shared__ float gates_s[128];
  __shared__ float scratch[NTHR];
  __shared__ float bg_s[128];
  __shared__ float bain_s[HHH];
  __shared__ float v_s[HHH];
  __shared__ float score_s[CHUNK];
  __shared__ float w_s[CHUNK];
  __shared__ float alive_s[CHUNK];
  __shared__ float bo_s[32];
  __shared__ float htl_s[32];
  __shared__ double c_d[32];                         // fp64 cell-state slice
  __shared__ float scale8_s[TEAM];
  __shared__ float mg_sh, lg_sh, mc_sh, m2_sh, cutoff_sh;
  __shared__ int idx_sh, bi_sh, rf_sh, ncand_sh;
  __shared__ int cand_s[MAXCAND];

  const int tid = threadIdx.x;
  const int b = blockIdx.x & 31;   // batch
  const int m = blockIdx.x >> 5;   // team member 0..7
  int* cnt = barp + b * 32;        // 128B-strided counters

  // ============ one-time: ctx_proj chunk -> cpT (transposed, fp64 acc) ============
  {
    float* raw = cpT;
    const float* ctxp = context + ((size_t)b * SSS + (size_t)m * CHUNK) * HHH;
    for (int i = tid; i < CHUNK * HHH; i += NTHR) raw[i] = ctxp[i];
    __syncthreads();
    const int cc = tid & 255;
    const int rgc = tid >> 8;  // row-group: rows rgc*64 ..
    double acc[2][32];
    double bc = (double)ba_ctx[cc];
    for (int half = 0; half < 2; ++half) {
#pragma unroll
      for (int k = 0; k < 32; ++k) acc[half][k] = 0.0;
      for (int h = 0; h < HHH; ++h) {
        double w = (double)Wa_ctx[h * HHH + cc];
        const float* base = &raw[(rgc * 64 + half * 32) * HHH + h];
#pragma unroll
        for (int k = 0; k < 32; ++k) acc[half][k] = fma((double)base[k * HHH], w, acc[half][k]);
      }
    }
    __syncthreads();  // all raw reads complete before transposed overwrite
#pragma unroll
    for (int half = 0; half < 2; ++half)
#pragma unroll
      for (int k = 0; k < 32; ++k) {
        int row = rgc * 64 + half * 32 + k;
        cpT[cc * CPAD + row] = (float)(acc[half][k] + bc);
      }
  }

  // ============ persistent weight registers ============
  const int q = tid & 127, rg = tid >> 7;                 // gates
  const int gcol = ((q >> 5) * 256) + m * 32 + (q & 31);
  float w_ih_r[64], w_hh_r[64];
#pragma unroll
  for (int k = 0; k < 64; ++k) {
    w_ih_r[k] = W_ih[(size_t)(rg * 64 + k) * 1024 + gcol];
    w_hh_r[k] = W_hh[(size_t)(rg * 64 + k) * 1024 + gcol];
  }
  const int hp = tid & 255, rh = tid >> 8;                // inp partial
  float w_ain_r[16];
#pragma unroll
  for (int k = 0; k < 16; ++k)
    w_ain_r[k] = Wa_in[(size_t)(m * 32 + rh * 16 + k) * HHH + hp];
  const int c2 = tid & 31, rgo = tid >> 5;                // h_out slice
  float w_out_r[32];
#pragma unroll
  for (int k = 0; k < 32; ++k)
    w_out_r[k] = W_out[(size_t)(rgo * 32 + k) * HHH + m * 32 + c2];

  // ============ LDS init ============
  if (tid < 128) {
    int j = ((tid >> 5) * 256) + m * 32 + (tid & 31);
    bg_s[tid] = b_ih[j] + b_hh[j];
    alive_s[tid] = 1.0f;
  }
  if (tid < 256) { bain_s[tid] = ba_in[tid]; v_s[tid] = v[tid]; }
  if (tid < 32)  { bo_s[tid] = b_out[m * 32 + tid]; c_d[tid] = (double)c0[b * HHH + m * 32 + tid]; }
  __syncthreads();

  int bart = 0;

  for (int t = 0; t < SSS; ++t) {
    // ------- A: gates -> LSTM(fp64 state) -> h_t slice -> pinp partial -------
    if (tid < 256) {
      if (t == 0) { x_s[tid] = dec0[b * EE + tid]; hx_s[tid] = h0[b * HHH + tid]; }
      else {
        int ix = idx_sh;
        x_s[tid] = enc[((size_t)b * SSS + ix) * EE + tid];
        hx_s[tid] = gload(&hbuf[b * HHH + tid]);
      }
    }
    __syncthreads();
    {
      float g = 0.0f;
      const float4* x4 = reinterpret_cast<const float4*>(&x_s[rg * 64]);
      const float4* h4 = reinterpret_cast<const float4*>(&hx_s[rg * 64]);
#pragma unroll
      for (int k = 0; k < 16; ++k) {
        float4 xv = x4[k];
        g = fmaf(w_ih_r[4 * k + 0], xv.x, g);
        g = fmaf(w_ih_r[4 * k + 1], xv.y, g);
        g = fmaf(w_ih_r[4 * k + 2], xv.z, g);
        g = fmaf(w_ih_r[4 * k + 3], xv.w, g);
      }
#pragma unroll
      for (int k = 0; k < 16; ++k) {
        float4 hv = h4[k];
        g = fmaf(w_hh_r[4 * k + 0], hv.x, g);
        g = fmaf(w_hh_r[4 * k + 1], hv.y, g);
        g = fmaf(w_hh_r[4 * k + 2], hv.z, g);
        g = fmaf(w_hh_r[4 * k + 3], hv.w, g);
      }
      scratch[tid] = g;  // rg*128+q == tid
    }
    __syncthreads();
    // parallel fp64 gate activations: each of 128 threads activates its own gate
    if (tid < 128) {
      float gsv = scratch[tid] + scratch[128 + tid] + scratch[256 + tid] + scratch[384 + tid] + bg_s[tid];
      double gd = (double)gsv;
      gact[tid] = (tid >= 64 && tid < 96) ? tanh(gd) : sigd(gd);  // [64,96) = g-gate
    }
    __syncthreads();
    if (tid < 32) {
      double cn = gact[32 + tid] * c_d[tid] + gact[tid] * gact[64 + tid];
      double ht = gact[96 + tid] * tanh(cn);
      c_d[tid] = cn;
      float htf = (float)ht;
      htl_s[tid] = htf;
      gstore(&htbuf[b * HHH + m * 32 + tid], htf);
    }
    __syncthreads();
    {
      float p = 0.0f;
#pragma unroll
      for (int k = 0; k < 16; ++k) p = fmaf(w_ain_r[k], htl_s[rh * 16 + k], p);
      scratch[rh * 256 + hp] = p;
    }
    __syncthreads();
    if (tid < 256) gstore(&pinp[((b * TEAM) + m) * HHH + tid], scratch[tid] + scratch[256 + tid]);
    bart += TEAM; team_bar(cnt, bart);

    // ------- B: thread-per-slot scores + chunk top-2 softmax stats + acc -------
    if (tid < 256) {
      double sd = (double)bain_s[tid];
#pragma unroll
      for (int w = 0; w < TEAM; ++w) sd += (double)gload(&pinp[((b * TEAM) + w) * HHH + tid]);
      inp_d[tid] = sd;
      ivp[2 * tid] = (float)sd; ivp[2 * tid + 1] = v_s[tid];
    }
    __syncthreads();
    {
      const int s = tid & 127, qq = tid >> 7;
      const float* cpc = &cpT[(qq * 64) * CPAD + s];
      const float2* iv = reinterpret_cast<const float2*>(&ivp[2 * qq * 64]);
      float acc0 = 0.0f, acc1 = 0.0f;
#pragma unroll 4
      for (int j = 0; j < 64; j += 2) {
        float2 iv0 = iv[j], iv1 = iv[j + 1];
        float t0 = fast_tanhf(iv0.x + cpc[j * CPAD]);
        float t1 = fast_tanhf(iv1.x + cpc[(j + 1) * CPAD]);
        acc0 = fmaf(iv0.y, t0, acc0);
        acc1 = fmaf(iv1.y, t1, acc1);
      }
      scratch[tid] = acc0 + acc1;  // qq*128+s == tid
    }
    __syncthreads();
    if (tid < 128)
      score_s[tid] = scratch[tid] + scratch[128 + tid] + scratch[256 + tid] + scratch[384 + tid];
    __syncthreads();
    if (tid < 64) {   // chunk top-2 (alive): v1 w/ first-occurrence idx, v2 value only
      float sa = (alive_s[tid] > 0.0f) ? score_s[tid] : NEG_INF;
      float sb = (alive_s[tid + 64] > 0.0f) ? score_s[tid + 64] : NEG_INF;
      float v1, v2; int i1;
      if (sb > sa) { v1 = sb; i1 = tid + 64; v2 = sa; }
      else         { v1 = sa; i1 = tid;      v2 = sb; }
#pragma unroll
      for (int d = 1; d < 64; d <<= 1) {
        float ov1 = __shfl_xor(v1, d); int oi1 = __shfl_xor(i1, d);
        float ov2 = __shfl_xor(v2, d);
        if (ov1 > v1 || (ov1 == v1 && oi1 < i1)) {
          v2 = fmaxf(v1, ov2); v1 = ov1; i1 = oi1;
        } else {
          v2 = fmaxf(v2, ov1);
        }
      }
      if (tid == 0) { mc_sh = v1; bi_sh = i1; m2_sh = v2; }
    }
    __syncthreads();
    if (tid < 128)
      w_s[tid] = (alive_s[tid] > 0.0f) ? __expf(score_s[tid] - mc_sh) : 0.0f;
    __syncthreads();
    if (tid < 64) {   // chunk l + stats write
      float l = w_s[tid] + w_s[tid + 64];
#pragma unroll
      for (int d = 1; d < 64; d <<= 1) l += __shfl_xor(l, d);
      if (tid == 0) {
        float* st = &stats[((b * TEAM) + m) * 4];
        gstore(&st[0], mc_sh);
        gstore(&st[1], l);
        gstore(&st[2], __int_as_float((mc_sh == NEG_INF) ? 0x7fffffff : (m * CHUNK + bi_sh)));
        gstore(&st[3], m2_sh);
      }
    }
    {
      const int h = tid & 255, sh = tid >> 8;
      const float* cpr = &cpT[h * CPAD + sh * 64];
      const float* wr = &w_s[sh * 64];
      float a = 0.0f;
#pragma unroll 8
      for (int j = 0; j < 64; ++j) a = fmaf(wr[j], cpr[j], a);
      scratch[sh * 256 + h] = a;
    }
    __syncthreads();
    if (tid < 256) gstore(&accb[((b * TEAM) + m) * HHH + tid], scratch[tid] + scratch[256 + tid]);
    bart += TEAM; team_bar(cnt, bart);

    // ------- C: combine (top-2 + margin) -> [refine] -> attn -> h_out -> outputs -------
    if (tid < 32)  // parallel stats gather: scratch[w*4+j]
      scratch[tid] = gload(&stats[((b * TEAM) + (tid >> 2)) * 4 + (tid & 3)]);
    __syncthreads();
    if (tid == 0) {
      float g1 = NEG_INF, g2 = NEG_INF; int gi = 0x7fffffff;
      float lg = 0.0f;
      float mcv[TEAM], lcv[TEAM];
#pragma unroll
      for (int w = 0; w < TEAM; ++w) {
        mcv[w] = scratch[w * 4 + 0]; lcv[w] = scratch[w * 4 + 1];
        int biv = __float_as_int(scratch[w * 4 + 2]); float v2v = scratch[w * 4 + 3];
        if (lcv[w] > 0.0f) {
          if (mcv[w] > g1 || (mcv[w] == g1 && biv < gi)) {
            g2 = fmaxf(g1, v2v); g1 = mcv[w]; gi = biv;
          } else {
            g2 = fmaxf(g2, mcv[w]);
          }
        }
      }
#pragma unroll
      for (int w = 0; w < TEAM; ++w) {
        float sw = (lcv[w] > 0.0f) ? __expf(mcv[w] - g1) : 0.0f;
        scale8_s[w] = sw; lg += lcv[w] * sw;
      }
      mg_sh = g1; lg_sh = lg; idx_sh = gi;
      rf_sh = (g2 > g1 - THETA) ? 1 : 0;   // margin < THETA -> exact refinement
      cutoff_sh = g1 - THETA;
    }
    __syncthreads();

    if (rf_sh) {
      // -- exact fp64 re-scoring of all near-top alive slots (deterministic team-wide) --
      if (tid == 0) {
        int nc = 0;
        for (int s2 = 0; s2 < CHUNK; ++s2)
          if (alive_s[s2] > 0.0f && score_s[s2] > cutoff_sh && nc < MAXCAND)
            cand_s[nc++] = s2;
        ncand_sh = nc;
      }
      __syncthreads();
      const int nc = ncand_sh;
      for (int ci = 0; ci < nc; ++ci) {
        const int slot = cand_s[ci];
        if (tid < 256) {
          const float* crow = context + ((size_t)b * SSS + (size_t)(m * CHUNK + slot)) * HHH;
          double acc = (double)ba_ctx[tid];
          for (int h2 = 0; h2 < HHH; ++h2)
            acc = fma((double)crow[h2], (double)Wa_ctx[h2 * HHH + tid], acc);
          double arg = inp_d[tid] + acc;
          dsc[tid] = (double)v_s[tid] * tanh(arg);
        }
        __syncthreads();
        if (tid < 64) {  // parallel fp64 reduce of 256 partials
          double se = dsc[tid] + dsc[tid + 64] + dsc[tid + 128] + dsc[tid + 192];
#pragma unroll
          for (int d = 1; d < 64; d <<= 1) se += __shfl_xor(se, d);
          if (tid == 0) {
            double* rw = &refws[(((size_t)b * TEAM) + m) * (1 + 2 * MAXCAND)];
            gstored(&rw[1 + 2 * ci], (double)(m * CHUNK + slot));
            gstored(&rw[2 + 2 * ci], se);
          }
        }
        __syncthreads();
      }
      if (tid == 0)
        gstored(&refws[(((size_t)b * TEAM) + m) * (1 + 2 * MAXCAND)], (double)nc);
      bart += TEAM; team_bar(cnt, bart);
      if (tid == 0) {
        double bs = -1.0e300; int bi2 = 0x7fffffff;
#pragma unroll
        for (int w = 0; w < TEAM; ++w) {
          const double* rw = &refws[(((size_t)b * TEAM) + w) * (1 + 2 * MAXCAND)];
          int wn = (int)gloadd(&rw[0]);
          for (int j2 = 0; j2 < wn; ++j2) {
            int ii = (int)gloadd(&rw[1 + 2 * j2]); double sv = gloadd(&rw[2 + 2 * j2]);
            if (sv > bs || (sv == bs && ii < bi2)) { bs = sv; bi2 = ii; }
          }
        }
        idx_sh = bi2;
      }
      __syncthreads();
    }

    if (tid < 256) {
      float a = 0.0f;
#pragma unroll
      for (int w = 0; w < TEAM; ++w) a += gload(&accb[((b * TEAM) + w) * HHH + tid]) * scale8_s[w];
      attn_s[tid] = a / lg_sh;
      ht_s[tid] = gload(&htbuf[b * HHH + tid]);
    }
    __syncthreads();
    {
      float hpart = 0.0f;
#pragma unroll
      for (int k = 0; k < 32; ++k) {
        int r = rgo * 32 + k;
        float vr = (r < 256) ? attn_s[r] : ht_s[r - 256];
        hpart = fmaf(w_out_r[k], vr, hpart);
      }
      scratch[rgo * 32 + c2] = hpart;
    }
    __syncthreads();
    if (tid < 32) {
      float s = bo_s[tid];
#pragma unroll
      for (int j = 0; j < 16; ++j) s += scratch[j * 32 + tid];
      gstore(&hbuf[b * HHH + m * 32 + tid], tanhf(s));
    }
    if (tid < 128) {
      float sc_ = score_s[tid];
      float al = (alive_s[tid] > 0.0f) ? __expf(sc_ - mg_sh) / lg_sh : 0.0f;
      __builtin_nontemporal_store(al,
          &out[(size_t)b * (SSS * SSS) + (size_t)t * SSS + m * CHUNK + tid]);
    }
    if (m == 0 && tid == 0)
      __builtin_nontemporal_store((float)idx_sh,
          &out[(size_t)BB * SSS * SSS + (size_t)b * SSS + t]);
    __syncthreads();   // alpha writes read alive_s before the clear below
    if (tid == 0 && (idx_sh >> 7) == m) alive_s[idx_sh & 127] = 0.0f;
    bart += TEAM; team_bar(cnt, bart);
  }
}

extern "C" void kernel_launch(void* const* d_in, const int* in_sizes, int n_in,
                              void* d_out, int out_size, void* d_ws, size_t ws_size,
                              hipStream_t stream) {
  (void)in_sizes; (void)n_in; (void)out_size; (void)ws_size;
  const float* enc     = (const float*)d_in[0];
  const float* dec0    = (const float*)d_in[1];
  const float* h0      = (const float*)d_in[2];
  const float* c0      = (const float*)d_in[3];
  const float* context = (const float*)d_in[4];
  const float* W_ih    = (const float*)d_in[5];
  const float* b_ih    = (const float*)d_in[6];
  const float* W_hh    = (const float*)d_in[7];
  const float* b_hh    = (const float*)d_in[8];
  const float* W_out   = (const float*)d_in[9];
  const float* b_out   = (const float*)d_in[10];
  const float* Wa_in   = (const float*)d_in[11];
  const float* ba_in   = (const float*)d_in[12];
  const float* Wa_ctx  = (const float*)d_in[13];
  const float* ba_ctx  = (const float*)d_in[14];
  const float* v       = (const float*)d_in[15];

  char* wsb   = (char*)d_ws;
  int*   barp  = (int*)wsb;                         // 4096 B
  float* hbuf  = (float*)(wsb + 4096);              // [32][256]           32768 B
  float* htbuf = hbuf + 32 * 256;                   // [32][256]           32768 B
  float* pinp  = htbuf + 32 * 256;                  // [32][8][256]       262144 B
  float* stats = pinp + 32 * 8 * 256;               // [32][8][4]           4096 B
  float* accb  = stats + 32 * 8 * 4;                // [32][8][256]       262144 B
  double* refws = (double*)(accb + 32 * 8 * 256);   // [32][8][17] dbl     34816 B  (tot ~633 KB)

  hipMemsetAsync(d_ws, 0, 4096, stream);            // reset barrier counters
  hipLaunchKernelGGL(ptrnet, dim3(256), dim3(NTHR), 0, stream,
                     enc, dec0, h0, c0, context,
                     W_ih, b_ih, W_hh, b_hh, W_out, b_out,
                     Wa_in, ba_in, Wa_ctx, ba_ctx, v,
                     (float*)d_out, barp, hbuf, htbuf, pinp, stats, accb, refws);
}

// Round 3
// 25107.787 us; speedup vs baseline: 1.3500x; 1.0016x over previous
//
#include <hip/hip_runtime.h>
#include <math.h>

#define BB 32
#define SSS 1024
#define EE 256
#define HHH 256
#define TEAM 8
#define CHUNK 128   // SSS / TEAM
#define NTHR 512
#define CPAD 129    // padded slot stride for transposed ctx_proj tile
#define THETA 3e-5f // refinement margin: >>10x the fp32 score-noise bound (~1e-6)
#define MAXCAND 8

#define NEG_INF (-__builtin_huge_valf())

__device__ __forceinline__ double sigd(double x) {
  return 1.0 / (1.0 + exp(-x));
}

// Fast fp32 tanh: 1 - 2/(1+e^{2x}) via v_exp_f32 + v_rcp_f32.
// abs error ~5e-7; safe at +-inf, no NaN path. Score noise stays ~1e-6 << THETA.
__device__ __forceinline__ float fast_tanhf(float x) {
  float e = __expf(2.0f * x);
  return 1.0f - 2.0f * __builtin_amdgcn_rcpf(1.0f + e);
}

// Cross-block data exchange: relaxed agent-scope atomics. These read/write the
// device coherence point directly, so barriers need no L2 inv/writeback for
// data correctness.
__device__ __forceinline__ void gstore(float* p, float v) {
  __hip_atomic_store(p, v, __ATOMIC_RELAXED, __HIP_MEMORY_SCOPE_AGENT);
}
__device__ __forceinline__ float gload(const float* p) {
  return __hip_atomic_load(p, __ATOMIC_RELAXED, __HIP_MEMORY_SCOPE_AGENT);
}
__device__ __forceinline__ void gstored(double* p, double v) {
  __hip_atomic_store(p, v, __ATOMIC_RELAXED, __HIP_MEMORY_SCOPE_AGENT);
}
__device__ __forceinline__ double gloadd(const double* p) {
  return __hip_atomic_load(p, __ATOMIC_RELAXED, __HIP_MEMORY_SCOPE_AGENT);
}

// Monotonic-counter team barrier (8 blocks). Release on arrival orders the
// arriving block's prior (atomic) stores; spin is RELAXED — no per-poll cache
// maintenance. Lockstep (3 barriers/step) keeps spin windows minimal: round-1
// showed that removing one barrier widens drift and costs MORE than it saves
// (FETCH 391->2269 MB of poll traffic, dur +1.5us/step).
__device__ __forceinline__ void team_bar(int* cnt, int target) {
  __syncthreads();
  if (threadIdx.x == 0) {
    __hip_atomic_fetch_add(cnt, 1, __ATOMIC_RELEASE, __HIP_MEMORY_SCOPE_AGENT);
    while (__hip_atomic_load(cnt, __ATOMIC_RELAXED, __HIP_MEMORY_SCOPE_AGENT) < target) {}
  }
  __syncthreads();
}

__global__ __launch_bounds__(NTHR, 2) void ptrnet(
    const float* __restrict__ enc, const float* __restrict__ dec0,
    const float* __restrict__ h0, const float* __restrict__ c0,
    const float* __restrict__ context,
    const float* __restrict__ W_ih, const float* __restrict__ b_ih,
    const float* __restrict__ W_hh, const float* __restrict__ b_hh,
    const float* __restrict__ W_out, const float* __restrict__ b_out,
    const float* __restrict__ Wa_in, const float* __restrict__ ba_in,
    const float* __restrict__ Wa_ctx, const float* __restrict__ ba_ctx,
    const float* __restrict__ v,
    float* __restrict__ out,
    int* __restrict__ barp,
    float* __restrict__ hbuf, float* __restrict__ htbuf,
    float* __restrict__ pinp, float* __restrict__ stats,
    float* __restrict__ accb, double* __restrict__ refws)
{
  // ---- LDS (~149 KB) ----
  __shared__ __align__(16) float cpT[HHH * CPAD];   // ctx_proj chunk, [h][slot], padded
  __shared__ double dsc[256];                        // fp64 refine scratch
  __shared__ __align__(8) float ivp[HHH * 2];       // interleaved (inp, v) fp32
  __shared__ double inp_d[HHH];                      // fp64 inp for refinement
  __shared__ double gact[128];                       // fp64 gate activations
  __shared__ float attn_s[HHH];
  __shared__ float ht_s[HHH];
  __shared__ __align__(16) float hx_s[HHH];
  __shared__ __align__(16) float x_s[EE];
  __shared__ float scratch[NTHR];
  __shared__ float bg_s[128];
  __shared__ float bain_s[HHH];
  __shared__ float v_s[HHH];
  __shared__ float score_s[CHUNK];
  __shared__ float w_s[CHUNK];
  __shared__ float alive_s[CHUNK];
  __shared__ float bo_s[32];
  __shared__ float htl_s[32];
  __shared__ double c_d[32];                         // fp64 cell-state slice
  __shared__ float scale8_s[TEAM];
  __shared__ float mg_sh, lg_sh, cutoff_sh;
  __shared__ int idx_sh, rf_sh, ncand_sh;
  __shared__ int cand_s[MAXCAND];

  const int tid = threadIdx.x;
  const int b = blockIdx.x & 31;   // batch
  const int m = blockIdx.x >> 5;   // team member 0..7
  int* cnt = barp + b * 32;        // 128B-strided counters

  // ============ one-time: ctx_proj chunk -> cpT (transposed, fp64 acc) ============
  {
    float* raw = cpT;
    const float* ctxp = context + ((size_t)b * SSS + (size_t)m * CHUNK) * HHH;
    for (int i = tid; i < CHUNK * HHH; i += NTHR) raw[i] = ctxp[i];
    __syncthreads();
    const int cc = tid & 255;
    const int rgc = tid >> 8;  // row-group: rows rgc*64 ..
    double acc[2][32];
    double bc = (double)ba_ctx[cc];
    for (int half = 0; half < 2; ++half) {
#pragma unroll
      for (int k = 0; k < 32; ++k) acc[half][k] = 0.0;
      for (int h = 0; h < HHH; ++h) {
        double w = (double)Wa_ctx[h * HHH + cc];
        const float* base = &raw[(rgc * 64 + half * 32) * HHH + h];
#pragma unroll
        for (int k = 0; k < 32; ++k) acc[half][k] = fma((double)base[k * HHH], w, acc[half][k]);
      }
    }
    __syncthreads();  // all raw reads complete before transposed overwrite
#pragma unroll
    for (int half = 0; half < 2; ++half)
#pragma unroll
      for (int k = 0; k < 32; ++k) {
        int row = rgc * 64 + half * 32 + k;
        cpT[cc * CPAD + row] = (float)(acc[half][k] + bc);
      }
  }

  // ============ persistent weight registers ============
  const int q = tid & 127, rg = tid >> 7;                 // gates
  const int gcol = ((q >> 5) * 256) + m * 32 + (q & 31);
  float w_ih_r[64], w_hh_r[64];
#pragma unroll
  for (int k = 0; k < 64; ++k) {
    w_ih_r[k] = W_ih[(size_t)(rg * 64 + k) * 1024 + gcol];
    w_hh_r[k] = W_hh[(size_t)(rg * 64 + k) * 1024 + gcol];
  }
  const int hp = tid & 255, rh = tid >> 8;                // inp partial
  float w_ain_r[16];
#pragma unroll
  for (int k = 0; k < 16; ++k)
    w_ain_r[k] = Wa_in[(size_t)(m * 32 + rh * 16 + k) * HHH + hp];
  const int c2 = tid & 31, rgo = tid >> 5;                // h_out slice
  float w_out_r[32];
#pragma unroll
  for (int k = 0; k < 32; ++k)
    w_out_r[k] = W_out[(size_t)(rgo * 32 + k) * HHH + m * 32 + c2];

  // ============ LDS init ============
  if (tid < 128) {
    int j = ((tid >> 5) * 256) + m * 32 + (tid & 31);
    bg_s[tid] = b_ih[j] + b_hh[j];
    alive_s[tid] = 1.0f;
  }
  if (tid < 256) { bain_s[tid] = ba_in[tid]; v_s[tid] = v[tid]; }
  if (tid < 32)  { bo_s[tid] = b_out[m * 32 + tid]; c_d[tid] = (double)c0[b * HHH + m * 32 + tid]; }
  __syncthreads();

  int bart = 0;

  for (int t = 0; t < SSS; ++t) {
    // ------- A: gates -> LSTM(fp64 state) -> h_t slice -> pinp partial -------
    if (tid < 256) {
      if (t == 0) { x_s[tid] = dec0[b * EE + tid]; hx_s[tid] = h0[b * HHH + tid]; }
      else {
        int ix = idx_sh;
        x_s[tid] = enc[((size_t)b * SSS + ix) * EE + tid];
        hx_s[tid] = gload(&hbuf[b * HHH + tid]);
      }
    }
    __syncthreads();
    {
      float g = 0.0f;
      const float4* x4 = reinterpret_cast<const float4*>(&x_s[rg * 64]);
      const float4* h4 = reinterpret_cast<const float4*>(&hx_s[rg * 64]);
#pragma unroll
      for (int k = 0; k < 16; ++k) {
        float4 xv = x4[k];
        g = fmaf(w_ih_r[4 * k + 0], xv.x, g);
        g = fmaf(w_ih_r[4 * k + 1], xv.y, g);
        g = fmaf(w_ih_r[4 * k + 2], xv.z, g);
        g = fmaf(w_ih_r[4 * k + 3], xv.w, g);
      }
#pragma unroll
      for (int k = 0; k < 16; ++k) {
        float4 hv = h4[k];
        g = fmaf(w_hh_r[4 * k + 0], hv.x, g);
        g = fmaf(w_hh_r[4 * k + 1], hv.y, g);
        g = fmaf(w_hh_r[4 * k + 2], hv.z, g);
        g = fmaf(w_hh_r[4 * k + 3], hv.w, g);
      }
      scratch[tid] = g;  // rg*128+q == tid
    }
    __syncthreads();
    // parallel fp64 gate activations: each of 128 threads activates its own gate
    if (tid < 128) {
      float gsv = scratch[tid] + scratch[128 + tid] + scratch[256 + tid] + scratch[384 + tid] + bg_s[tid];
      double gd = (double)gsv;
      gact[tid] = (tid >= 64 && tid < 96) ? tanh(gd) : sigd(gd);  // [64,96) = g-gate
    }
    __syncthreads();
    if (tid < 32) {
      double cn = gact[32 + tid] * c_d[tid] + gact[tid] * gact[64 + tid];
      double ht = gact[96 + tid] * tanh(cn);
      c_d[tid] = cn;
      float htf = (float)ht;
      htl_s[tid] = htf;
      gstore(&htbuf[b * HHH + m * 32 + tid], htf);
    }
    __syncthreads();
    {
      float p = 0.0f;
#pragma unroll
      for (int k = 0; k < 16; ++k) p = fmaf(w_ain_r[k], htl_s[rh * 16 + k], p);
      scratch[rh * 256 + hp] = p;
    }
    __syncthreads();
    if (tid < 256) gstore(&pinp[((b * TEAM) + m) * HHH + tid], scratch[tid] + scratch[256 + tid]);
    bart += TEAM; team_bar(cnt, bart);

    // ------- B: thread-per-slot scores + chunk top-2 softmax stats + acc -------
    if (tid < 256) {
      double sd = (double)bain_s[tid];
#pragma unroll
      for (int w = 0; w < TEAM; ++w) sd += (double)gload(&pinp[((b * TEAM) + w) * HHH + tid]);
      inp_d[tid] = sd;
      ivp[2 * tid] = (float)sd; ivp[2 * tid + 1] = v_s[tid];
    }
    __syncthreads();
    {
      const int s = tid & 127, qq = tid >> 7;
      const float* cpc = &cpT[(qq * 64) * CPAD + s];
      const float2* iv = reinterpret_cast<const float2*>(&ivp[2 * qq * 64]);
      float acc0 = 0.0f, acc1 = 0.0f;
#pragma unroll 4
      for (int j = 0; j < 64; j += 2) {
        float2 iv0 = iv[j], iv1 = iv[j + 1];
        float t0 = fast_tanhf(iv0.x + cpc[j * CPAD]);
        float t1 = fast_tanhf(iv1.x + cpc[(j + 1) * CPAD]);
        acc0 = fmaf(iv0.y, t0, acc0);
        acc1 = fmaf(iv1.y, t1, acc1);
      }
      scratch[tid] = acc0 + acc1;  // qq*128+s == tid
    }
    __syncthreads();
    if (tid < 128)
      score_s[tid] = scratch[tid] + scratch[128 + tid] + scratch[256 + tid] + scratch[384 + tid];
    __syncthreads();
    // fused wave-0 tail: top-2 butterfly leaves ALL lanes with the global
    // (v1,i1,v2), so w_s / l / stats need no intervening __syncthreads.
    if (tid < 64) {
      float sa = (alive_s[tid] > 0.0f) ? score_s[tid] : NEG_INF;
      float sb = (alive_s[tid + 64] > 0.0f) ? score_s[tid + 64] : NEG_INF;
      float v1, v2; int i1;
      if (sb > sa) { v1 = sb; i1 = tid + 64; v2 = sa; }
      else         { v1 = sa; i1 = tid;      v2 = sb; }
#pragma unroll
      for (int d = 1; d < 64; d <<= 1) {
        float ov1 = __shfl_xor(v1, d); int oi1 = __shfl_xor(i1, d);
        float ov2 = __shfl_xor(v2, d);
        if (ov1 > v1 || (ov1 == v1 && oi1 < i1)) {
          v2 = fmaxf(v1, ov2); v1 = ov1; i1 = oi1;
        } else {
          v2 = fmaxf(v2, ov1);
        }
      }
      float w0 = (alive_s[tid] > 0.0f) ? __expf(score_s[tid] - v1) : 0.0f;
      float w1 = (alive_s[tid + 64] > 0.0f) ? __expf(score_s[tid + 64] - v1) : 0.0f;
      w_s[tid] = w0; w_s[tid + 64] = w1;
      float l = w0 + w1;
#pragma unroll
      for (int d = 1; d < 64; d <<= 1) l += __shfl_xor(l, d);
      if (tid == 0) {
        float* st = &stats[((b * TEAM) + m) * 4];
        gstore(&st[0], v1);
        gstore(&st[1], l);
        gstore(&st[2], __int_as_float((v1 == NEG_INF) ? 0x7fffffff : (m * CHUNK + i1)));
        gstore(&st[3], v2);
      }
    }
    __syncthreads();   // w_s ready for the acc pass
    {
      const int h = tid & 255, sh = tid >> 8;
      const float* cpr = &cpT[h * CPAD + sh * 64];
      const float* wr = &w_s[sh * 64];
      float a = 0.0f;
#pragma unroll 8
      for (int j = 0; j < 64; ++j) a = fmaf(wr[j], cpr[j], a);
      scratch[sh * 256 + h] = a;
    }
    __syncthreads();
    if (tid < 256) gstore(&accb[((b * TEAM) + m) * HHH + tid], scratch[tid] + scratch[256 + tid]);
    bart += TEAM; team_bar(cnt, bart);

    // ------- C: combine (top-2 + margin) -> [refine] -> attn -> h_out -> outputs -------
    // Prefetch accb + htbuf CONCURRENTLY with the stats gather: all loads issue
    // before the same sync, so one MALL round covers both (was two serial rounds).
    float accp[TEAM]; float htp = 0.0f;
    if (tid < 256) {
#pragma unroll
      for (int w = 0; w < TEAM; ++w) accp[w] = gload(&accb[((b * TEAM) + w) * HHH + tid]);
      htp = gload(&htbuf[b * HHH + tid]);
    }
    if (tid < 32)  // parallel stats gather: scratch[w*4+j]
      scratch[tid] = gload(&stats[((b * TEAM) + (tid >> 2)) * 4 + (tid & 3)]);
    __syncthreads();
    if (tid == 0) {
      float g1 = NEG_INF, g2 = NEG_INF; int gi = 0x7fffffff;
      float lg = 0.0f;
      float mcv[TEAM], lcv[TEAM];
#pragma unroll
      for (int w = 0; w < TEAM; ++w) {
        mcv[w] = scratch[w * 4 + 0]; lcv[w] = scratch[w * 4 + 1];
        int biv = __float_as_int(scratch[w * 4 + 2]); float v2v = scratch[w * 4 + 3];
        if (lcv[w] > 0.0f) {
          if (mcv[w] > g1 || (mcv[w] == g1 && biv < gi)) {
            g2 = fmaxf(g1, v2v); g1 = mcv[w]; gi = biv;
          } else {
            g2 = fmaxf(g2, mcv[w]);
          }
        }
      }
#pragma unroll
      for (int w = 0; w < TEAM; ++w) {
        float sw = (lcv[w] > 0.0f) ? __expf(mcv[w] - g1) : 0.0f;
        scale8_s[w] = sw; lg += lcv[w] * sw;
      }
      mg_sh = g1; lg_sh = lg; idx_sh = gi;
      rf_sh = (g2 > g1 - THETA) ? 1 : 0;   // margin < THETA -> exact refinement
      cutoff_sh = g1 - THETA;
    }
    __syncthreads();

    // Early alpha stores: depend only on mg/lg/scores/alive (NOT on refine —
    // softmax is argmax-independent). Issued here so the HBM drain overlaps
    // refine/attn/h_out instead of stalling bar3's release.
    if (tid < 128) {
      float sc_ = score_s[tid];
      float al = (alive_s[tid] > 0.0f) ? __expf(sc_ - mg_sh) / lg_sh : 0.0f;
      __builtin_nontemporal_store(al,
          &out[(size_t)b * (SSS * SSS) + (size_t)t * SSS + m * CHUNK + tid]);
    }

    if (rf_sh) {
      // -- exact fp64 re-scoring of all near-top alive slots (deterministic team-wide) --
      if (tid == 0) {
        int nc = 0;
        for (int s2 = 0; s2 < CHUNK; ++s2)
          if (alive_s[s2] > 0.0f && score_s[s2] > cutoff_sh && nc < MAXCAND)
            cand_s[nc++] = s2;
        ncand_sh = nc;
      }
      __syncthreads();
      const int nc = ncand_sh;
      for (int ci = 0; ci < nc; ++ci) {
        const int slot = cand_s[ci];
        if (tid < 256) {
          const float* crow = context + ((size_t)b * SSS + (size_t)(m * CHUNK + slot)) * HHH;
          double acc = (double)ba_ctx[tid];
          for (int h2 = 0; h2 < HHH; ++h2)
            acc = fma((double)crow[h2], (double)Wa_ctx[h2 * HHH + tid], acc);
          double arg = inp_d[tid] + acc;
          dsc[tid] = (double)v_s[tid] * tanh(arg);
        }
        __syncthreads();
        if (tid < 64) {  // parallel fp64 reduce of 256 partials
          double se = dsc[tid] + dsc[tid + 64] + dsc[tid + 128] + dsc[tid + 192];
#pragma unroll
          for (int d = 1; d < 64; d <<= 1) se += __shfl_xor(se, d);
          if (tid == 0) {
            double* rw = &refws[(((size_t)b * TEAM) + m) * (1 + 2 * MAXCAND)];
            gstored(&rw[1 + 2 * ci], (double)(m * CHUNK + slot));
            gstored(&rw[2 + 2 * ci], se);
          }
        }
        __syncthreads();
      }
      if (tid == 0)
        gstored(&refws[(((size_t)b * TEAM) + m) * (1 + 2 * MAXCAND)], (double)nc);
      bart += TEAM; team_bar(cnt, bart);
      if (tid == 0) {
        double bs = -1.0e300; int bi2 = 0x7fffffff;
#pragma unroll
        for (int w = 0; w < TEAM; ++w) {
          const double* rw = &refws[(((size_t)b * TEAM) + w) * (1 + 2 * MAXCAND)];
          int wn = (int)gloadd(&rw[0]);
          for (int j2 = 0; j2 < wn; ++j2) {
            int ii = (int)gloadd(&rw[1 + 2 * j2]); double sv = gloadd(&rw[2 + 2 * j2]);
            if (sv > bs || (sv == bs && ii < bi2)) { bs = sv; bi2 = ii; }
          }
        }
        idx_sh = bi2;
      }
      __syncthreads();
    }

    if (tid < 256) {
      float a = 0.0f;
#pragma unroll
      for (int w = 0; w < TEAM; ++w) a = fmaf(accp[w], scale8_s[w], a);
      attn_s[tid] = a / lg_sh;
      ht_s[tid] = htp;
    }
    __syncthreads();
    {
      float hpart = 0.0f;
#pragma unroll
      for (int k = 0; k < 32; ++k) {
        int r = rgo * 32 + k;
        float vr = (r < 256) ? attn_s[r] : ht_s[r - 256];
        hpart = fmaf(w_out_r[k], vr, hpart);
      }
      scratch[rgo * 32 + c2] = hpart;
    }
    __syncthreads();
    if (tid < 32) {
      float s = bo_s[tid];
#pragma unroll
      for (int j = 0; j < 16; ++j) s += scratch[j * 32 + tid];
      gstore(&hbuf[b * HHH + m * 32 + tid], tanhf(s));
    }
    if (m == 0 && tid == 0)
      __builtin_nontemporal_store((float)idx_sh,
          &out[(size_t)BB * SSS * SSS + (size_t)b * SSS + t]);
    // alive clear: every thread's alpha read of alive_s is separated from this
    // write by at least one __syncthreads above (attn->h_out), so no extra sync.
    if (tid == 0 && (idx_sh >> 7) == m) alive_s[idx_sh & 127] = 0.0f;
    bart += TEAM; team_bar(cnt, bart);
  }
}

extern "C" void kernel_launch(void* const* d_in, const int* in_sizes, int n_in,
                              void* d_out, int out_size, void* d_ws, size_t ws_size,
                              hipStream_t stream) {
  (void)in_sizes; (void)n_in; (void)out_size; (void)ws_size;
  const float* enc     = (const float*)d_in[0];
  const float* dec0    = (const float*)d_in[1];
  const float* h0      = (const float*)d_in[2];
  const float* c0      = (const float*)d_in[3];
  const float* context = (const float*)d_in[4];
  const float* W_ih    = (const float*)d_in[5];
  const float* b_ih    = (const float*)d_in[6];
  const float* W_hh    = (const float*)d_in[7];
  const float* b_hh    = (const float*)d_in[8];
  const float* W_out   = (const float*)d_in[9];
  const float* b_out   = (const float*)d_in[10];
  const float* Wa_in   = (const float*)d_in[11];
  const float* ba_in   = (const float*)d_in[12];
  const float* Wa_ctx  = (const float*)d_in[13];
  const float* ba_ctx  = (const float*)d_in[14];
  const float* v       = (const float*)d_in[15];

  char* wsb   = (char*)d_ws;
  int*   barp  = (int*)wsb;                         // 4096 B
  float* hbuf  = (float*)(wsb + 4096);              // [32][256]           32768 B
  float* htbuf = hbuf + 32 * 256;                   // [32][256]           32768 B
  float* pinp  = htbuf + 32 * 256;                  // [32][8][256]       262144 B
  float* stats = pinp + 32 * 8 * 256;               // [32][8][4]           4096 B
  float* accb  = stats + 32 * 8 * 4;                // [32][8][256]       262144 B
  double* refws = (double*)(accb + 32 * 8 * 256);   // [32][8][17] dbl     34816 B  (tot ~633 KB)

  hipMemsetAsync(d_ws, 0, 4096, stream);            // reset barrier counters
  hipLaunchKernelGGL(ptrnet, dim3(256), dim3(NTHR), 0, stream,
                     enc, dec0, h0, c0, context,
                     W_ih, b_ih, W_hh, b_hh, W_out, b_out,
                     Wa_in, ba_in, Wa_ctx, ba_ctx, v,
                     (float*)d_out, barp, hbuf, htbuf, pinp, stats, accb, refws);
}